// Round 5
// baseline (318.898 us; speedup 1.0000x reference)
//
#include <hip/hip_runtime.h>
#include <math.h>

typedef unsigned short u16;
typedef unsigned int u32;
typedef __attribute__((ext_vector_type(8))) short short8;    // bf16x8 MFMA frag
typedef __attribute__((ext_vector_type(8))) u16 ushort8;
typedef __attribute__((ext_vector_type(4))) float f32x4;

__device__ __forceinline__ float bf2f(u16 u) {
    union { u32 i; float f; } c; c.i = ((u32)u) << 16; return c.f;
}
__device__ __forceinline__ u16 f2bf(float f) {
    union { float f; u32 i; } c; c.f = f;
    u32 r = (c.i + 0x7FFFu + ((c.i >> 16) & 1u)) >> 16;
    return (u16)r;
}

// async global(16B) -> LDS, per-lane source addr, wave-linear LDS dest
__device__ __forceinline__ void gload16(void* lds, const void* g) {
    __builtin_amdgcn_global_load_lds(
        (const __attribute__((address_space(1))) u32*)g,
        (__attribute__((address_space(3))) u32*)lds,
        16, 0, 0);
}

// ---------------------------------------------------------------------------
// Fused Q (split-bf16, 3-pass) + K (single-pass) projection.
// A = hhi/hlo [nPad][512]; Bq = Wqhi/Wqlo, Bk = Wkhi (all [n][k]).
// Q -> f32 (rows < Mq), K -> bf16 (all rows). K reuses A-hi fragments.
// ---------------------------------------------------------------------------
__global__ __launch_bounds__(256) void gemm_qk(
    const u16* __restrict__ Ahi, const u16* __restrict__ Alo,
    const u16* __restrict__ Bqh, const u16* __restrict__ Bql,
    const u16* __restrict__ Bkh,
    const float* __restrict__ bqp, const float* __restrict__ bkp,
    float* __restrict__ Qout, u16* __restrict__ Kout, int Mq)
{
    __shared__ u16 sAh[128 * 32], sAl[128 * 32];
    __shared__ u16 sQh[128 * 32], sQl[128 * 32], sKh[128 * 32];

    const int tid  = threadIdx.x;
    const int wave = tid >> 6;
    const int lane = tid & 63;
    const int m0 = blockIdx.x * 128;
    const int n0 = blockIdx.y * 128;
    const int wr = (wave >> 1) * 64;
    const int wc = (wave & 1) * 64;

    f32x4 accQ[4][4], accK[4][4];
#pragma unroll
    for (int i = 0; i < 4; ++i)
#pragma unroll
        for (int j = 0; j < 4; ++j) {
            accQ[i][j] = (f32x4){0.f, 0.f, 0.f, 0.f};
            accK[i][j] = (f32x4){0.f, 0.f, 0.f, 0.f};
        }

    const int srow = lane >> 2;          // 0..15
    const int scol = (lane & 3) * 8;     // bf16 elems
    const size_t gOffA = (size_t)(m0 + wave * 32 + srow) * 512 + scol;
    const size_t gOffB = (size_t)(n0 + wave * 32 + srow) * 512 + scol;
    const int lOff = wave * 1024 + srow * 32 + scol;

    const int paOff = (wr + (lane & 15)) * 32 + (lane >> 4) * 8;
    const int pbOff = (wc + (lane & 15)) * 32 + (lane >> 4) * 8;

    for (int kt = 0; kt < 16; ++kt) {
        const int ko = kt * 32;
        gload16(&sAh[lOff],       Ahi + gOffA + ko);
        gload16(&sAh[lOff + 512], Ahi + gOffA + ko + 16 * 512);
        gload16(&sAl[lOff],       Alo + gOffA + ko);
        gload16(&sAl[lOff + 512], Alo + gOffA + ko + 16 * 512);
        gload16(&sQh[lOff],       Bqh + gOffB + ko);
        gload16(&sQh[lOff + 512], Bqh + gOffB + ko + 16 * 512);
        gload16(&sQl[lOff],       Bql + gOffB + ko);
        gload16(&sQl[lOff + 512], Bql + gOffB + ko + 16 * 512);
        gload16(&sKh[lOff],       Bkh + gOffB + ko);
        gload16(&sKh[lOff + 512], Bkh + gOffB + ko + 16 * 512);
        __syncthreads();

        short8 af0[4], af1[4], bt[4], bl[4];
#pragma unroll
        for (int i = 0; i < 4; ++i) af0[i] = *(const short8*)(&sAh[paOff + i * 512]);
#pragma unroll
        for (int i = 0; i < 4; ++i) af1[i] = *(const short8*)(&sAl[paOff + i * 512]);

        // K pass (reuses af0)
#pragma unroll
        for (int j = 0; j < 4; ++j) bt[j] = *(const short8*)(&sKh[pbOff + j * 512]);
#pragma unroll
        for (int i = 0; i < 4; ++i)
#pragma unroll
            for (int j = 0; j < 4; ++j)
                accK[i][j] = __builtin_amdgcn_mfma_f32_16x16x32_bf16(
                    af0[i], bt[j], accK[i][j], 0, 0, 0);

        // Q hi*hi
#pragma unroll
        for (int j = 0; j < 4; ++j) bt[j] = *(const short8*)(&sQh[pbOff + j * 512]);
#pragma unroll
        for (int i = 0; i < 4; ++i)
#pragma unroll
            for (int j = 0; j < 4; ++j)
                accQ[i][j] = __builtin_amdgcn_mfma_f32_16x16x32_bf16(
                    af0[i], bt[j], accQ[i][j], 0, 0, 0);

        // Q lo*hi + hi*lo
#pragma unroll
        for (int j = 0; j < 4; ++j) bl[j] = *(const short8*)(&sQl[pbOff + j * 512]);
#pragma unroll
        for (int i = 0; i < 4; ++i)
#pragma unroll
            for (int j = 0; j < 4; ++j) {
                accQ[i][j] = __builtin_amdgcn_mfma_f32_16x16x32_bf16(
                    af1[i], bt[j], accQ[i][j], 0, 0, 0);
                accQ[i][j] = __builtin_amdgcn_mfma_f32_16x16x32_bf16(
                    af0[i], bl[j], accQ[i][j], 0, 0, 0);
            }
        __syncthreads();
    }

    const int ccol  = n0 + wc + (lane & 15);
    const int crow0 = m0 + wr + (lane >> 4) * 4;
#pragma unroll
    for (int j = 0; j < 4; ++j) {
        const float bQ = bqp[ccol + j * 16];
        const float bK = bkp[ccol + j * 16];
#pragma unroll
        for (int i = 0; i < 4; ++i) {
#pragma unroll
            for (int r = 0; r < 4; ++r) {
                int row = crow0 + i * 16 + r;
                size_t off = (size_t)row * 512 + ccol + j * 16;
                Kout[off] = f2bf(accK[i][j][r] + bK);
                if (row < Mq) Qout[off] = accQ[i][j][r] + bQ;
            }
        }
    }
}

// ---------------------------------------------------------------------------
// Single-pass bf16 GEMM (Wo projection): C f32 = A bf16 @ Bt + bias
// ---------------------------------------------------------------------------
__global__ __launch_bounds__(256) void gemm_single(
    const u16* __restrict__ A, const u16* __restrict__ Bt,
    const float* __restrict__ bias, float* __restrict__ C, int Mout)
{
    __shared__ u16 As[128 * 32];
    __shared__ u16 Bs[128 * 32];

    const int tid  = threadIdx.x;
    const int wave = tid >> 6;
    const int lane = tid & 63;
    const int m0 = blockIdx.x * 128;
    const int n0 = blockIdx.y * 128;
    const int wr = (wave >> 1) * 64;
    const int wc = (wave & 1) * 64;

    f32x4 acc[4][4];
#pragma unroll
    for (int i = 0; i < 4; ++i)
#pragma unroll
        for (int j = 0; j < 4; ++j) acc[i][j] = (f32x4){0.f, 0.f, 0.f, 0.f};

    const int srow = lane >> 2;
    const int scol = (lane & 3) * 8;
    const size_t gOffA = (size_t)(m0 + wave * 32 + srow) * 512 + scol;
    const size_t gOffB = (size_t)(n0 + wave * 32 + srow) * 512 + scol;
    const int lOff = wave * 1024 + srow * 32 + scol;

    const int paOff = (wr + (lane & 15)) * 32 + (lane >> 4) * 8;
    const int pbOff = (wc + (lane & 15)) * 32 + (lane >> 4) * 8;

    for (int kt = 0; kt < 16; ++kt) {
        const int ko = kt * 32;
        gload16(&As[lOff],       A + gOffA + ko);
        gload16(&As[lOff + 512], A + gOffA + ko + 16 * 512);
        gload16(&Bs[lOff],       Bt + gOffB + ko);
        gload16(&Bs[lOff + 512], Bt + gOffB + ko + 16 * 512);
        __syncthreads();

        short8 af[4], bf[4];
#pragma unroll
        for (int i = 0; i < 4; ++i) af[i] = *(const short8*)(&As[paOff + i * 512]);
#pragma unroll
        for (int j = 0; j < 4; ++j) bf[j] = *(const short8*)(&Bs[pbOff + j * 512]);
#pragma unroll
        for (int i = 0; i < 4; ++i)
#pragma unroll
            for (int j = 0; j < 4; ++j)
                acc[i][j] = __builtin_amdgcn_mfma_f32_16x16x32_bf16(
                    af[i], bf[j], acc[i][j], 0, 0, 0);
        __syncthreads();
    }

    const int ccol  = n0 + wc + (lane & 15);
    const int crow0 = m0 + wr + (lane >> 4) * 4;
#pragma unroll
    for (int j = 0; j < 4; ++j) {
        const float b = bias[ccol + j * 16];
#pragma unroll
        for (int i = 0; i < 4; ++i) {
#pragma unroll
            for (int r = 0; r < 4; ++r) {
                int row = crow0 + i * 16 + r;
                if (row < Mout)
                    C[(size_t)row * 512 + ccol + j * 16] = acc[i][j][r] + b;
            }
        }
    }
}

// ---------------------------------------------------------------------------
// prep: h f32 -> bf16 hi+lo, pad rows zeroed
// ---------------------------------------------------------------------------
__global__ __launch_bounds__(256) void conv_h(
    const float* __restrict__ h, u16* __restrict__ hhi, u16* __restrict__ hlo, int nN)
{
    int t = blockIdx.x * 256 + threadIdx.x;      // one thread = 8 elems
    size_t e = (size_t)t * 8;
    int row = (int)(e >> 9);
    ushort8 ohi, olo;
    if (row < nN) {
        f32x4 a = *(const f32x4*)(h + e);
        f32x4 b = *(const f32x4*)(h + e + 4);
        float x[8] = {a.x, a.y, a.z, a.w, b.x, b.y, b.z, b.w};
#pragma unroll
        for (int i = 0; i < 8; ++i) {
            u16 hi = f2bf(x[i]);
            ohi[i] = hi;
            olo[i] = f2bf(x[i] - bf2f(hi));
        }
    } else {
        ohi = (ushort8){0,0,0,0,0,0,0,0};
        olo = (ushort8){0,0,0,0,0,0,0,0};
    }
    *(ushort8*)(hhi + e) = ohi;
    *(ushort8*)(hlo + e) = olo;
}

// ---------------------------------------------------------------------------
// Weight transposes via LDS 64x65 tiles; coalesced global reads.
// z=0: Wqt[j][k] = Wq[k][perm(j)] (hi+lo)   perm(j) = (j&63)*8 + (j>>6)
// z=1: Wkt[j][k] = Wk[k][perm(j)] (hi)
// z=2: Wot[c][j] = Wo[perm(j)][c] (hi) + bias perms
// ---------------------------------------------------------------------------
__global__ __launch_bounds__(256) void conv_w(
    const float* __restrict__ Wq, const float* __restrict__ Wk,
    const float* __restrict__ Wo, const float* __restrict__ bq,
    const float* __restrict__ bk,
    u16* __restrict__ Wqhi, u16* __restrict__ Wqlo, u16* __restrict__ Wkhi,
    u16* __restrict__ Wot, float* __restrict__ bqp, float* __restrict__ bkp)
{
    __shared__ float T[64][65];
    const int tid = threadIdx.x;
    const int z = blockIdx.z;
    const int X = blockIdx.x * 64;   // out-col tile (k for z<2, j for z=2)
    const int Y = blockIdx.y * 64;   // p-tile (z<2) / c-tile (z=2)

    // load: coalesced 64x64 f32 tile
    const int r4 = tid >> 4;          // 0..15
    const int c4 = (tid & 15) * 4;    // 0..60
    if (z < 2) {
        const float* W = z ? Wk : Wq;
#pragma unroll
        for (int rr = 0; rr < 64; rr += 16) {
            f32x4 v = *(const f32x4*)(W + (size_t)(X + rr + r4) * 512 + Y + c4);
            T[rr + r4][c4 + 0] = v.x; T[rr + r4][c4 + 1] = v.y;
            T[rr + r4][c4 + 2] = v.z; T[rr + r4][c4 + 3] = v.w;
        }
    } else {
#pragma unroll
        for (int rr = 0; rr < 64; rr += 16) {
            int p2 = (rr + r4) * 8 + (X >> 6);   // perm(X + rr + r4)
            f32x4 v = *(const f32x4*)(Wo + (size_t)p2 * 512 + Y + c4);
            T[rr + r4][c4 + 0] = v.x; T[rr + r4][c4 + 1] = v.y;
            T[rr + r4][c4 + 2] = v.z; T[rr + r4][c4 + 3] = v.w;
        }
    }
    __syncthreads();

    // write: each thread emits 16 u16 (32B) of one output row
    const int cc = tid >> 2;
    const int ks = (tid & 3) * 16;
    const int pc = Y + cc;
    const int ro = (z < 2) ? ((pc & 7) * 64 + (pc >> 3)) : pc;
    ushort8 h0, h1, l0, l1;
#pragma unroll
    for (int t = 0; t < 8; ++t) {
        float v = T[ks + t][cc];
        h0[t] = f2bf(v); l0[t] = f2bf(v - bf2f(h0[t]));
        v = T[ks + 8 + t][cc];
        h1[t] = f2bf(v); l1[t] = f2bf(v - bf2f(h1[t]));
    }
    size_t o = (size_t)ro * 512 + X + ks;
    if (z == 0) {
        *(ushort8*)(Wqhi + o) = h0; *(ushort8*)(Wqhi + o + 8) = h1;
        *(ushort8*)(Wqlo + o) = l0; *(ushort8*)(Wqlo + o + 8) = l1;
    } else if (z == 1) {
        *(ushort8*)(Wkhi + o) = h0; *(ushort8*)(Wkhi + o + 8) = h1;
    } else {
        *(ushort8*)(Wot + o) = h0; *(ushort8*)(Wot + o + 8) = h1;
        if (blockIdx.x == 0 && blockIdx.y == 0) {
            for (int b = tid; b < 512; b += 256) {
                int pp = (b & 63) * 8 + (b >> 6);
                bqp[b] = bq[pp];
                bkp[b] = bk[pp];
            }
        }
    }
}

// ---------------------------------------------------------------------------
// CSR build: histogram -> hierarchical scan -> scatter (stores cols directly)
// ---------------------------------------------------------------------------
__global__ void hist_kernel(const int* __restrict__ rows, int* __restrict__ deg, int E)
{
    int i = blockIdx.x * 256 + threadIdx.x;
    if (i < E) atomicAdd(&deg[rows[i]], 1);
}

#define SCAN_CHUNK 2048

__global__ __launch_bounds__(256) void scan_partial(
    const int* __restrict__ deg, int* __restrict__ bsum, int n)
{
    int base = blockIdx.x * SCAN_CHUNK;
    int t = threadIdx.x;
    int s = 0;
    for (int i = t; i < SCAN_CHUNK; i += 256) {
        int g = base + i;
        s += (g < n) ? deg[g] : 0;
    }
#pragma unroll
    for (int off = 1; off < 64; off <<= 1) s += __shfl_xor(s, off, 64);
    __shared__ int ws[4];
    if ((t & 63) == 0) ws[t >> 6] = s;
    __syncthreads();
    if (t == 0) bsum[blockIdx.x] = ws[0] + ws[1] + ws[2] + ws[3];
}

__global__ __launch_bounds__(64) void scan_bsum(
    int* __restrict__ bsum, int nb, int* __restrict__ rowptr, int n)
{
    int l = threadIdx.x;
    int v = (l < nb) ? bsum[l] : 0;
    int orig = v;
#pragma unroll
    for (int off = 1; off < 64; off <<= 1) {
        int x = __shfl_up(v, off, 64);
        if (l >= off) v += x;
    }
    if (l < nb) bsum[l] = v - orig;       // exclusive
    if (l == nb - 1) rowptr[n] = v;       // total
}

__global__ __launch_bounds__(256) void scan_final(
    const int* __restrict__ deg, const int* __restrict__ bsum,
    int* __restrict__ rowptr, int* __restrict__ cursor, int n)
{
    int t = threadIdx.x;
    int base = blockIdx.x * SCAN_CHUNK + t * 8;
    int v[8];
    int s = 0;
#pragma unroll
    for (int i = 0; i < 8; ++i) {
        int g = base + i;
        v[i] = (g < n) ? deg[g] : 0;
        s += v[i];
    }
    int lane = t & 63, w = t >> 6;
    int inc = s;
#pragma unroll
    for (int off = 1; off < 64; off <<= 1) {
        int x = __shfl_up(inc, off, 64);
        if (lane >= off) inc += x;
    }
    __shared__ int wsum[4];
    if (lane == 63) wsum[w] = inc;
    __syncthreads();
    int excl = bsum[blockIdx.x] + inc - s;
    for (int i = 0; i < w; ++i) excl += wsum[i];
#pragma unroll
    for (int i = 0; i < 8; ++i) {
        int g = base + i;
        if (g < n) { rowptr[g] = excl; cursor[g] = excl; }
        excl += v[i];
    }
}

__global__ void scatter_kernel(const int* __restrict__ rows, const int* __restrict__ cols,
                               int* __restrict__ cursor, int* __restrict__ colc, int E)
{
    int i = blockIdx.x * 256 + threadIdx.x;
    if (i < E) {
        int pos = atomicAdd(&cursor[rows[i]], 1);
        colc[pos] = cols[i];
    }
}

// ---------------------------------------------------------------------------
// Fused SDDMM + online segment softmax + SpMM. Head-major layout:
// lane l -> head l>>3, dims (l&7)*8..+7. One wave per node, 4 nodes/block.
// 2-edge unroll + depth-2 prefetch. v == k (source bug): the K row loaded
// for the dot is reused for aggregation.
// ---------------------------------------------------------------------------
__global__ __launch_bounds__(256) void node_agg(
    const float* __restrict__ Q, const u16* __restrict__ Kb,
    const int* __restrict__ rowptr, const int* __restrict__ colc,
    u16* __restrict__ aggb, int nN)
{
    int node = blockIdx.x * 4 + (threadIdx.x >> 6);
    int lane = threadIdx.x & 63;
    if (node >= nN) return;
    size_t base = (size_t)node * 512 + lane * 8;

    float q[8];
    {
        f32x4 qa = __builtin_nontemporal_load((const f32x4*)(Q + base));
        f32x4 qb = __builtin_nontemporal_load((const f32x4*)(Q + base + 4));
#pragma unroll
        for (int i = 0; i < 4; ++i) { q[i] = qa[i]; q[i + 4] = qb[i]; }
    }

    int start = rowptr[node];
    int deg   = rowptr[node + 1] - start;
    const int* cp = colc + start;
    const size_t loff = (size_t)lane * 8;

    float m = -__builtin_inff();
    float den = 0.f;
    float acc[8];
#pragma unroll
    for (int i = 0; i < 8; ++i) acc[i] = 0.f;

    if (deg > 0) {
        ushort8 k0 = *(const ushort8*)(Kb + (size_t)cp[0] * 512 + loff);
        ushort8 k1 = *(const ushort8*)(Kb + (size_t)cp[deg > 1 ? 1 : 0] * 512 + loff);
        for (int j = 0; j < deg; j += 2) {
            int iC = (j + 2 < deg) ? j + 2 : deg - 1;
            int iD = (j + 3 < deg) ? j + 3 : deg - 1;
            ushort8 n0 = *(const ushort8*)(Kb + (size_t)cp[iC] * 512 + loff);
            ushort8 n1 = *(const ushort8*)(Kb + (size_t)cp[iD] * 512 + loff);

            float kf0[8], kf1[8];
#pragma unroll
            for (int i = 0; i < 8; ++i) { kf0[i] = bf2f(k0[i]); kf1[i] = bf2f(k1[i]); }
            float p0 = 0.f, p1 = 0.f;
#pragma unroll
            for (int i = 0; i < 8; ++i) {
                p0 = fmaf(q[i], kf0[i], p0);
                p1 = fmaf(q[i], kf1[i], p1);
            }
            p0 += __shfl_xor(p0, 1, 64);  p1 += __shfl_xor(p1, 1, 64);
            p0 += __shfl_xor(p0, 2, 64);  p1 += __shfl_xor(p1, 2, 64);
            p0 += __shfl_xor(p0, 4, 64);  p1 += __shfl_xor(p1, 4, 64);

            // defer-max (T13, THR=8), wave-uniform decision
            if (__any(p0 > m + 8.f)) {
                float mn = fmaxf(m, p0);
                float sc = __expf(m - mn);   // first edge: exp(-inf)=0
                den *= sc;
#pragma unroll
                for (int i = 0; i < 8; ++i) acc[i] *= sc;
                m = mn;
            }
            float w0 = __expf(p0 - m);       // bounded by e^8
            den += w0;
#pragma unroll
            for (int i = 0; i < 8; ++i) acc[i] = fmaf(w0, kf0[i], acc[i]);

            if (j + 1 < deg) {
                if (__any(p1 > m + 8.f)) {
                    float mn = fmaxf(m, p1);
                    float sc = __expf(m - mn);
                    den *= sc;
#pragma unroll
                    for (int i = 0; i < 8; ++i) acc[i] *= sc;
                    m = mn;
                }
                float w1 = __expf(p1 - m);
                den += w1;
#pragma unroll
                for (int i = 0; i < 8; ++i) acc[i] = fmaf(w1, kf1[i], acc[i]);
            }
            k0 = n0; k1 = n1;
        }
    }

    float inv = (deg > 0) ? 1.f / den : 0.f;
    ushort8 o;
#pragma unroll
    for (int i = 0; i < 8; ++i) o[i] = f2bf(acc[i] * inv);
    __builtin_nontemporal_store(o, (ushort8*)(aggb + base));
}

// ---------------------------------------------------------------------------
extern "C" void kernel_launch(void* const* d_in, const int* in_sizes, int n_in,
                              void* d_out, int out_size, void* d_ws, size_t ws_size,
                              hipStream_t stream)
{
    const float* h  = (const float*)d_in[0];
    const float* Wq = (const float*)d_in[1];
    const float* bq = (const float*)d_in[2];
    const float* Wk = (const float*)d_in[3];
    const float* bk = (const float*)d_in[4];
    const float* Wo = (const float*)d_in[5];
    const float* bo = (const float*)d_in[6];
    const int* rows = (const int*)d_in[7];
    const int* cols = (const int*)d_in[8];
    float* out = (float*)d_out;

    const int HID = 512;
    const int nN  = in_sizes[0] / HID;              // 25000
    const int E   = in_sizes[7];                    // 400000
    const int nPad = (nN + 127) & ~127;             // 25088
    const int nb = (nN + SCAN_CHUNK - 1) / SCAN_CHUNK;  // 13

    // Q (f32) lives in d_out: fully consumed by node_agg before the final
    // Wo GEMM overwrites d_out with the real output.
    float* Q = out;

    // workspace layout (all 16B-aligned)
    char* w = (char*)d_ws;
    u16* Kb   = (u16*)w;  w += (size_t)nPad * HID * 2;  // 25.7 MB
    u16* hhi  = (u16*)w;  w += (size_t)nPad * HID * 2;  // 25.7 MB (reused as agg)
    u16* hlo  = (u16*)w;  w += (size_t)nPad * HID * 2;  // 25.7 MB
    u16* Wqhi = (u16*)w;  w += 512 * 512 * 2;
    u16* Wqlo = (u16*)w;  w += 512 * 512 * 2;
    u16* Wkhi = (u16*)w;  w += 512 * 512 * 2;
    u16* Wot  = (u16*)w;  w += 512 * 512 * 2;
    float* bqp = (float*)w;  w += 512 * 4;
    float* bkp = (float*)w;  w += 512 * 4;
    int* rowptr = (int*)w;   w += (size_t)(nN + 1) * 4;
    int* cursor = (int*)w;   w += (size_t)nN * 4;
    int* deg    = (int*)w;   w += (size_t)nN * 4;
    int* bsum   = (int*)w;   w += 64 * 4;
    int* colc   = (int*)w;   /* E*4 */

    // CSR build
    hipMemsetAsync(deg, 0, (size_t)nN * sizeof(int), stream);
    hist_kernel<<<(E + 255) / 256, 256, 0, stream>>>(rows, deg, E);
    scan_partial<<<nb, 256, 0, stream>>>(deg, bsum, nN);
    scan_bsum<<<1, 64, 0, stream>>>(bsum, nb, rowptr, nN);
    scan_final<<<nb, 256, 0, stream>>>(deg, bsum, rowptr, cursor, nN);
    scatter_kernel<<<(E + 255) / 256, 256, 0, stream>>>(rows, cols, cursor, colc, E);

    // conversions
    conv_h<<<(nPad * (HID / 8) + 255) / 256, 256, 0, stream>>>(h, hhi, hlo, nN);
    conv_w<<<dim3(8, 8, 3), 256, 0, stream>>>(Wq, Wk, Wo, bq, bk,
                                              Wqhi, Wqlo, Wkhi, Wot, bqp, bkp);

    // fused Q (split) + K (single) projection, head-major outputs
    gemm_qk<<<dim3(nPad / 128, 4), 256, 0, stream>>>(
        hhi, hlo, Wqhi, Wqlo, Wkhi, bqp, bkp, Q, Kb, nN);

    // fused SDDMM + softmax + aggregate -> bf16 agg (overwrites hhi)
    node_agg<<<(nN + 3) / 4, 256, 0, stream>>>(Q, Kb, rowptr, colc, hhi, nN);

    // output projection
    gemm_single<<<dim3(nPad / 128, 4), 256, 0, stream>>>(hhi, Wot, bo, out, nN);
}

// Round 6
// 296.868 us; speedup vs baseline: 1.0742x; 1.0742x over previous
//
#include <hip/hip_runtime.h>
#include <math.h>

typedef unsigned short u16;
typedef unsigned int u32;
typedef __attribute__((ext_vector_type(8))) short short8;    // bf16x8 MFMA frag
typedef __attribute__((ext_vector_type(8))) u16 ushort8;
typedef __attribute__((ext_vector_type(4))) float f32x4;

__device__ __forceinline__ float bf2f(u16 u) {
    union { u32 i; float f; } c; c.i = ((u32)u) << 16; return c.f;
}
__device__ __forceinline__ u16 f2bf(float f) {
    union { float f; u32 i; } c; c.f = f;
    u32 r = (c.i + 0x7FFFu + ((c.i >> 16) & 1u)) >> 16;
    return (u16)r;
}

// async global(16B) -> LDS, per-lane source addr, wave-linear LDS dest
__device__ __forceinline__ void gload16(void* lds, const void* g) {
    __builtin_amdgcn_global_load_lds(
        (const __attribute__((address_space(1))) u32*)g,
        (__attribute__((address_space(3))) u32*)lds,
        16, 0, 0);
}

// ---------------------------------------------------------------------------
// C[M,512] = A[M,512] @ Bt[512,512]([n][k]) + bias.
// SPLIT=1: A,B given as bf16 hi+lo pairs; C = Ahi*Bhi + Alo*Bhi + Ahi*Blo.
// OUTMODE 0: f32 store, 1: bf16 store. Stores guarded by row < Mout.
//
// LDS tile [128][32]u16 with XOR slot-swizzle to kill ds_read bank conflicts
// (rule #21: linear gload_lds dest + inverse-swizzled GLOBAL source column +
//  swizzled read slot). slot'(row) = slot ^ ((row>>1)&3); rows 0-7 then span
// bank groups {0,16,4,20,8,24,12,28} -> 2-way only (free, m136).
// ---------------------------------------------------------------------------
template <int SPLIT, int OUTMODE>
__global__ __launch_bounds__(256) void gemm_mfma(
    const u16* __restrict__ Ahi, const u16* __restrict__ Alo,
    const u16* __restrict__ Bhi, const u16* __restrict__ Blo,
    const float* __restrict__ bias, void* __restrict__ Cout, int Mout)
{
    constexpr int NB = SPLIT ? 2 : 1;
    __shared__ u16 As[NB][128 * 32];
    __shared__ u16 Bs[NB][128 * 32];

    const int tid  = threadIdx.x;
    const int wave = tid >> 6;
    const int lane = tid & 63;
    const int m0 = blockIdx.x * 128;
    const int n0 = blockIdx.y * 128;
    const int wr = (wave >> 1) * 64;
    const int wc = (wave & 1) * 64;

    f32x4 acc[4][4];
#pragma unroll
    for (int i = 0; i < 4; ++i)
#pragma unroll
        for (int j = 0; j < 4; ++j) acc[i][j] = (f32x4){0.f, 0.f, 0.f, 0.f};

    // staging: wave handles rows wave*32 .. +31 of the 128-row tile.
    // LDS dest linear; global column slot inverse-swizzled.
    const int srow  = lane >> 2;                              // 0..15
    const int scolG = ((lane & 3) ^ ((srow >> 1) & 3)) * 8;   // swizzled global col
    const size_t gOffA = (size_t)(m0 + wave * 32 + srow) * 512 + scolG;
    const size_t gOffB = (size_t)(n0 + wave * 32 + srow) * 512 + scolG;
    const int lOff = wave * 1024 + srow * 32 + (lane & 3) * 8;  // linear dest

    // read: lane wants global slot (lane>>4) of row wr/wc + (lane&15) (+16i);
    // f(row) = ((row>>1)&3) depends only on (lane&15) here (wr,16i ≡ 0 mod 4).
    const int fR = ((lane & 15) >> 1) & 3;
    const int paOff = (wr + (lane & 15)) * 32 + (((lane >> 4) ^ fR)) * 8;
    const int pbOff = (wc + (lane & 15)) * 32 + (((lane >> 4) ^ fR)) * 8;

    for (int kt = 0; kt < 16; ++kt) {
        const int ko = kt * 32;
        gload16(&As[0][lOff],       Ahi + gOffA + ko);
        gload16(&As[0][lOff + 512], Ahi + gOffA + ko + 16 * 512);
        gload16(&Bs[0][lOff],       Bhi + gOffB + ko);
        gload16(&Bs[0][lOff + 512], Bhi + gOffB + ko + 16 * 512);
        if constexpr (SPLIT) {
            gload16(&As[1][lOff],       Alo + gOffA + ko);
            gload16(&As[1][lOff + 512], Alo + gOffA + ko + 16 * 512);
            gload16(&Bs[1][lOff],       Blo + gOffB + ko);
            gload16(&Bs[1][lOff + 512], Blo + gOffB + ko + 16 * 512);
        }
        __syncthreads();   // compiler drains vmcnt before barrier

        short8 af[NB][4], bf[NB][4];
#pragma unroll
        for (int i = 0; i < 4; ++i) af[0][i] = *(const short8*)(&As[0][paOff + i * 512]);
#pragma unroll
        for (int j = 0; j < 4; ++j) bf[0][j] = *(const short8*)(&Bs[0][pbOff + j * 512]);
        if constexpr (SPLIT) {
#pragma unroll
            for (int i = 0; i < 4; ++i) af[1][i] = *(const short8*)(&As[1][paOff + i * 512]);
#pragma unroll
            for (int j = 0; j < 4; ++j) bf[1][j] = *(const short8*)(&Bs[1][pbOff + j * 512]);
        }
#pragma unroll
        for (int i = 0; i < 4; ++i)
#pragma unroll
            for (int j = 0; j < 4; ++j) {
                acc[i][j] = __builtin_amdgcn_mfma_f32_16x16x32_bf16(
                    af[0][i], bf[0][j], acc[i][j], 0, 0, 0);
                if constexpr (SPLIT) {
                    acc[i][j] = __builtin_amdgcn_mfma_f32_16x16x32_bf16(
                        af[1][i], bf[0][j], acc[i][j], 0, 0, 0);
                    acc[i][j] = __builtin_amdgcn_mfma_f32_16x16x32_bf16(
                        af[0][i], bf[1][j], acc[i][j], 0, 0, 0);
                }
            }
        __syncthreads();
    }

    // epilogue: C/D layout col=lane&15, row=(lane>>4)*4+reg
    const int ccol  = n0 + wc + (lane & 15);
    const int crow0 = m0 + wr + (lane >> 4) * 4;
#pragma unroll
    for (int j = 0; j < 4; ++j) {
        const float b = bias[ccol + j * 16];
#pragma unroll
        for (int i = 0; i < 4; ++i) {
#pragma unroll
            for (int r = 0; r < 4; ++r) {
                int row = crow0 + i * 16 + r;
                if (row < Mout) {
                    float v = acc[i][j][r] + b;
                    size_t off = (size_t)row * 512 + ccol + j * 16;
                    if (OUTMODE == 0) ((float*)Cout)[off] = v;
                    else              ((u16*)Cout)[off] = f2bf(v);
                }
            }
        }
    }
}

// ---------------------------------------------------------------------------
// prep: h f32 -> bf16 hi+lo, pad rows zeroed
// ---------------------------------------------------------------------------
__global__ __launch_bounds__(256) void conv_h(
    const float* __restrict__ h, u16* __restrict__ hhi, u16* __restrict__ hlo, int nN)
{
    int t = blockIdx.x * 256 + threadIdx.x;      // one thread = 8 elems
    size_t e = (size_t)t * 8;
    int row = (int)(e >> 9);
    ushort8 ohi, olo;
    if (row < nN) {
        f32x4 a = *(const f32x4*)(h + e);
        f32x4 b = *(const f32x4*)(h + e + 4);
        float x[8] = {a.x, a.y, a.z, a.w, b.x, b.y, b.z, b.w};
#pragma unroll
        for (int i = 0; i < 8; ++i) {
            u16 hi = f2bf(x[i]);
            ohi[i] = hi;
            olo[i] = f2bf(x[i] - bf2f(hi));
        }
    } else {
        ohi = (ushort8){0,0,0,0,0,0,0,0};
        olo = (ushort8){0,0,0,0,0,0,0,0};
    }
    *(ushort8*)(hhi + e) = ohi;
    *(ushort8*)(hlo + e) = olo;
}

// ---------------------------------------------------------------------------
// Weight transposes via LDS 64x65 tiles; coalesced global reads.
// z=0: Wqt[j][k] = Wq[k][perm(j)] (hi+lo)   perm(j) = (j&63)*8 + (j>>6)
// z=1: Wkt[j][k] = Wk[k][perm(j)] (hi)
// z=2: Wot[c][j] = Wo[perm(j)][c] (hi) + bias perms
// ---------------------------------------------------------------------------
__global__ __launch_bounds__(256) void conv_w(
    const float* __restrict__ Wq, const float* __restrict__ Wk,
    const float* __restrict__ Wo, const float* __restrict__ bq,
    const float* __restrict__ bk,
    u16* __restrict__ Wqhi, u16* __restrict__ Wqlo, u16* __restrict__ Wkhi,
    u16* __restrict__ Wot, float* __restrict__ bqp, float* __restrict__ bkp)
{
    __shared__ float T[64][65];
    const int tid = threadIdx.x;
    const int z = blockIdx.z;
    const int X = blockIdx.x * 64;   // out-col tile (k for z<2, j for z=2)
    const int Y = blockIdx.y * 64;   // p-tile (z<2) / c-tile (z=2)

    // load: coalesced 64x64 f32 tile
    const int r4 = tid >> 4;          // 0..15
    const int c4 = (tid & 15) * 4;    // 0..60
    if (z < 2) {
        const float* W = z ? Wk : Wq;
#pragma unroll
        for (int rr = 0; rr < 64; rr += 16) {
            f32x4 v = *(const f32x4*)(W + (size_t)(X + rr + r4) * 512 + Y + c4);
            T[rr + r4][c4 + 0] = v.x; T[rr + r4][c4 + 1] = v.y;
            T[rr + r4][c4 + 2] = v.z; T[rr + r4][c4 + 3] = v.w;
        }
    } else {
#pragma unroll
        for (int rr = 0; rr < 64; rr += 16) {
            int p2 = (rr + r4) * 8 + (X >> 6);   // perm(X + rr + r4)
            f32x4 v = *(const f32x4*)(Wo + (size_t)p2 * 512 + Y + c4);
            T[rr + r4][c4 + 0] = v.x; T[rr + r4][c4 + 1] = v.y;
            T[rr + r4][c4 + 2] = v.z; T[rr + r4][c4 + 3] = v.w;
        }
    }
    __syncthreads();

    // write: each thread emits 16 u16 (32B) of one output row
    const int cc = tid >> 2;
    const int ks = (tid & 3) * 16;
    const int pc = Y + cc;
    const int ro = (z < 2) ? ((pc & 7) * 64 + (pc >> 3)) : pc;
    ushort8 h0, h1, l0, l1;
#pragma unroll
    for (int t = 0; t < 8; ++t) {
        float v = T[ks + t][cc];
        h0[t] = f2bf(v); l0[t] = f2bf(v - bf2f(h0[t]));
        v = T[ks + 8 + t][cc];
        h1[t] = f2bf(v); l1[t] = f2bf(v - bf2f(h1[t]));
    }
    size_t o = (size_t)ro * 512 + X + ks;
    if (z == 0) {
        *(ushort8*)(Wqhi + o) = h0; *(ushort8*)(Wqhi + o + 8) = h1;
        *(ushort8*)(Wqlo + o) = l0; *(ushort8*)(Wqlo + o + 8) = l1;
    } else if (z == 1) {
        *(ushort8*)(Wkhi + o) = h0; *(ushort8*)(Wkhi + o + 8) = h1;
    } else {
        *(ushort8*)(Wot + o) = h0; *(ushort8*)(Wot + o + 8) = h1;
        if (blockIdx.x == 0 && blockIdx.y == 0) {
            for (int b = tid; b < 512; b += 256) {
                int pp = (b & 63) * 8 + (b >> 6);
                bqp[b] = bq[pp];
                bkp[b] = bk[pp];
            }
        }
    }
}

// ---------------------------------------------------------------------------
// CSR build: histogram -> hierarchical scan -> scatter (stores cols directly)
// ---------------------------------------------------------------------------
__global__ void hist_kernel(const int* __restrict__ rows, int* __restrict__ deg, int E)
{
    int i = blockIdx.x * 256 + threadIdx.x;
    if (i < E) atomicAdd(&deg[rows[i]], 1);
}

#define SCAN_CHUNK 2048

__global__ __launch_bounds__(256) void scan_partial(
    const int* __restrict__ deg, int* __restrict__ bsum, int n)
{
    int base = blockIdx.x * SCAN_CHUNK;
    int t = threadIdx.x;
    int s = 0;
    for (int i = t; i < SCAN_CHUNK; i += 256) {
        int g = base + i;
        s += (g < n) ? deg[g] : 0;
    }
#pragma unroll
    for (int off = 1; off < 64; off <<= 1) s += __shfl_xor(s, off, 64);
    __shared__ int ws[4];
    if ((t & 63) == 0) ws[t >> 6] = s;
    __syncthreads();
    if (t == 0) bsum[blockIdx.x] = ws[0] + ws[1] + ws[2] + ws[3];
}

__global__ __launch_bounds__(64) void scan_bsum(
    int* __restrict__ bsum, int nb, int* __restrict__ rowptr, int n)
{
    int l = threadIdx.x;
    int v = (l < nb) ? bsum[l] : 0;
    int orig = v;
#pragma unroll
    for (int off = 1; off < 64; off <<= 1) {
        int x = __shfl_up(v, off, 64);
        if (l >= off) v += x;
    }
    if (l < nb) bsum[l] = v - orig;       // exclusive
    if (l == nb - 1) rowptr[n] = v;       // total
}

__global__ __launch_bounds__(256) void scan_final(
    const int* __restrict__ deg, const int* __restrict__ bsum,
    int* __restrict__ rowptr, int* __restrict__ cursor, int n)
{
    int t = threadIdx.x;
    int base = blockIdx.x * SCAN_CHUNK + t * 8;
    int v[8];
    int s = 0;
#pragma unroll
    for (int i = 0; i < 8; ++i) {
        int g = base + i;
        v[i] = (g < n) ? deg[g] : 0;
        s += v[i];
    }
    int lane = t & 63, w = t >> 6;
    int inc = s;
#pragma unroll
    for (int off = 1; off < 64; off <<= 1) {
        int x = __shfl_up(inc, off, 64);
        if (lane >= off) inc += x;
    }
    __shared__ int wsum[4];
    if (lane == 63) wsum[w] = inc;
    __syncthreads();
    int excl = bsum[blockIdx.x] + inc - s;
    for (int i = 0; i < w; ++i) excl += wsum[i];
#pragma unroll
    for (int i = 0; i < 8; ++i) {
        int g = base + i;
        if (g < n) { rowptr[g] = excl; cursor[g] = excl; }
        excl += v[i];
    }
}

__global__ void scatter_kernel(const int* __restrict__ rows, const int* __restrict__ cols,
                               int* __restrict__ cursor, int* __restrict__ colc, int E)
{
    int i = blockIdx.x * 256 + threadIdx.x;
    if (i < E) {
        int pos = atomicAdd(&cursor[rows[i]], 1);
        colc[pos] = cols[i];
    }
}

// ---------------------------------------------------------------------------
// Fused SDDMM + online segment softmax + SpMM. Head-major layout:
// lane l -> head l>>3, dims (l&7)*8..+7. One wave per node, 4 nodes/block.
// 4-edge unroll + depth-4 prefetch; one defer-max check per 4-edge group.
// v == k (source bug): the K row loaded for the dot is reused for aggregation.
// ---------------------------------------------------------------------------
__global__ __launch_bounds__(256) void node_agg(
    const float* __restrict__ Q, const u16* __restrict__ Kb,
    const int* __restrict__ rowptr, const int* __restrict__ colc,
    u16* __restrict__ aggb, int nN)
{
    int node = blockIdx.x * 4 + (threadIdx.x >> 6);
    int lane = threadIdx.x & 63;
    if (node >= nN) return;
    size_t base = (size_t)node * 512 + lane * 8;

    float q[8];
    {
        f32x4 qa = __builtin_nontemporal_load((const f32x4*)(Q + base));
        f32x4 qb = __builtin_nontemporal_load((const f32x4*)(Q + base + 4));
#pragma unroll
        for (int i = 0; i < 4; ++i) { q[i] = qa[i]; q[i + 4] = qb[i]; }
    }

    int start = rowptr[node];
    int deg   = rowptr[node + 1] - start;
    const int* cp = colc + start;
    const size_t loff = (size_t)lane * 8;

    float m = -__builtin_inff();
    float den = 0.f;
    float acc[8];
#pragma unroll
    for (int i = 0; i < 8; ++i) acc[i] = 0.f;

    if (deg > 0) {
        const int dl = deg - 1;
        ushort8 k0 = *(const ushort8*)(Kb + (size_t)cp[0] * 512 + loff);
        ushort8 k1 = *(const ushort8*)(Kb + (size_t)cp[1 < dl ? 1 : dl] * 512 + loff);
        ushort8 k2 = *(const ushort8*)(Kb + (size_t)cp[2 < dl ? 2 : dl] * 512 + loff);
        ushort8 k3 = *(const ushort8*)(Kb + (size_t)cp[3 < dl ? 3 : dl] * 512 + loff);
        for (int j = 0; j < deg; j += 4) {
            int i4 = j + 4 < dl ? j + 4 : dl;
            int i5 = j + 5 < dl ? j + 5 : dl;
            int i6 = j + 6 < dl ? j + 6 : dl;
            int i7 = j + 7 < dl ? j + 7 : dl;
            ushort8 n0 = *(const ushort8*)(Kb + (size_t)cp[i4] * 512 + loff);
            ushort8 n1 = *(const ushort8*)(Kb + (size_t)cp[i5] * 512 + loff);
            ushort8 n2 = *(const ushort8*)(Kb + (size_t)cp[i6] * 512 + loff);
            ushort8 n3 = *(const ushort8*)(Kb + (size_t)cp[i7] * 512 + loff);

            float kf0[8], kf1[8], kf2[8], kf3[8];
#pragma unroll
            for (int i = 0; i < 8; ++i) {
                kf0[i] = bf2f(k0[i]); kf1[i] = bf2f(k1[i]);
                kf2[i] = bf2f(k2[i]); kf3[i] = bf2f(k3[i]);
            }
            float p0 = 0.f, p1 = 0.f, p2 = 0.f, p3 = 0.f;
#pragma unroll
            for (int i = 0; i < 8; ++i) {
                p0 = fmaf(q[i], kf0[i], p0);
                p1 = fmaf(q[i], kf1[i], p1);
                p2 = fmaf(q[i], kf2[i], p2);
                p3 = fmaf(q[i], kf3[i], p3);
            }
#pragma unroll
            for (int off = 1; off < 8; off <<= 1) {
                p0 += __shfl_xor(p0, off, 64);
                p1 += __shfl_xor(p1, off, 64);
                p2 += __shfl_xor(p2, off, 64);
                p3 += __shfl_xor(p3, off, 64);
            }

            // defer-max (T13, THR=8): one check per 4-edge group
            float pm = fmaxf(fmaxf(p0, p1), fmaxf(p2, p3));
            if (__any(pm > m + 8.f)) {
                float mn = fmaxf(m, pm);
                float sc = __expf(m - mn);   // first group: exp(-inf)=0
                den *= sc;
#pragma unroll
                for (int i = 0; i < 8; ++i) acc[i] *= sc;
                m = mn;
            }
            float w0 = __expf(p0 - m);       // each bounded by e^8
            float w1 = (j + 1 < deg) ? __expf(p1 - m) : 0.f;
            float w2 = (j + 2 < deg) ? __expf(p2 - m) : 0.f;
            float w3 = (j + 3 < deg) ? __expf(p3 - m) : 0.f;
            den += (w0 + w1) + (w2 + w3);
#pragma unroll
            for (int i = 0; i < 8; ++i)
                acc[i] = fmaf(w3, kf3[i], fmaf(w2, kf2[i],
                         fmaf(w1, kf1[i], fmaf(w0, kf0[i], acc[i]))));
            k0 = n0; k1 = n1; k2 = n2; k3 = n3;
        }
    }

    float inv = (deg > 0) ? 1.f / den : 0.f;
    ushort8 o;
#pragma unroll
    for (int i = 0; i < 8; ++i) o[i] = f2bf(acc[i] * inv);
    __builtin_nontemporal_store(o, (ushort8*)(aggb + base));
}

// ---------------------------------------------------------------------------
extern "C" void kernel_launch(void* const* d_in, const int* in_sizes, int n_in,
                              void* d_out, int out_size, void* d_ws, size_t ws_size,
                              hipStream_t stream)
{
    const float* h  = (const float*)d_in[0];
    const float* Wq = (const float*)d_in[1];
    const float* bq = (const float*)d_in[2];
    const float* Wk = (const float*)d_in[3];
    const float* bk = (const float*)d_in[4];
    const float* Wo = (const float*)d_in[5];
    const float* bo = (const float*)d_in[6];
    const int* rows = (const int*)d_in[7];
    const int* cols = (const int*)d_in[8];
    float* out = (float*)d_out;

    const int HID = 512;
    const int nN  = in_sizes[0] / HID;              // 25000
    const int E   = in_sizes[7];                    // 400000
    const int nPad = (nN + 127) & ~127;             // 25088
    const int nb = (nN + SCAN_CHUNK - 1) / SCAN_CHUNK;  // 13

    // Q (f32) lives in d_out: fully consumed by node_agg before the final
    // Wo GEMM overwrites d_out with the real output.
    float* Q = out;

    // workspace layout (all 16B-aligned)
    char* w = (char*)d_ws;
    u16* Kb   = (u16*)w;  w += (size_t)nPad * HID * 2;  // 25.7 MB
    u16* hhi  = (u16*)w;  w += (size_t)nPad * HID * 2;  // 25.7 MB (reused as agg)
    u16* hlo  = (u16*)w;  w += (size_t)nPad * HID * 2;  // 25.7 MB
    u16* Wqhi = (u16*)w;  w += 512 * 512 * 2;
    u16* Wqlo = (u16*)w;  w += 512 * 512 * 2;
    u16* Wkhi = (u16*)w;  w += 512 * 512 * 2;
    u16* Wot  = (u16*)w;  w += 512 * 512 * 2;
    float* bqp = (float*)w;  w += 512 * 4;
    float* bkp = (float*)w;  w += 512 * 4;
    int* rowptr = (int*)w;   w += (size_t)(nN + 1) * 4;
    int* cursor = (int*)w;   w += (size_t)nN * 4;
    int* deg    = (int*)w;   w += (size_t)nN * 4;
    int* bsum   = (int*)w;   w += 64 * 4;
    int* colc   = (int*)w;   /* E*4 */

    // CSR build
    hipMemsetAsync(deg, 0, (size_t)nN * sizeof(int), stream);
    hist_kernel<<<(E + 255) / 256, 256, 0, stream>>>(rows, deg, E);
    scan_partial<<<nb, 256, 0, stream>>>(deg, bsum, nN);
    scan_bsum<<<1, 64, 0, stream>>>(bsum, nb, rowptr, nN);
    scan_final<<<nb, 256, 0, stream>>>(deg, bsum, rowptr, cursor, nN);
    scatter_kernel<<<(E + 255) / 256, 256, 0, stream>>>(rows, cols, cursor, colc, E);

    // conversions
    conv_h<<<(nPad * (HID / 8) + 255) / 256, 256, 0, stream>>>(h, hhi, hlo, nN);
    conv_w<<<dim3(8, 8, 3), 256, 0, stream>>>(Wq, Wk, Wo, bq, bk,
                                              Wqhi, Wqlo, Wkhi, Wot, bqp, bkp);

    // projections (head-major outputs); Q split-bf16 3-pass, K single-pass
    dim3 gg(nPad / 128, 4);
    gemm_mfma<1, 0><<<gg, 256, 0, stream>>>(hhi, hlo, Wqhi, Wqlo, bqp, Q,  nN);        // Q f32
    gemm_mfma<0, 1><<<gg, 256, 0, stream>>>(hhi, nullptr, Wkhi, nullptr, bkp, Kb, nPad); // K bf16

    // fused SDDMM + softmax + aggregate -> bf16 agg (overwrites hhi)
    node_agg<<<(nN + 3) / 4, 256, 0, stream>>>(Q, Kb, rowptr, colc, hhi, nN);

    // output projection
    gemm_mfma<0, 0><<<gg, 256, 0, stream>>>(hhi, nullptr, Wot, nullptr, bo, out, nN);
}

// Round 7
// 263.651 us; speedup vs baseline: 1.2095x; 1.1260x over previous
//
#include <hip/hip_runtime.h>
#include <math.h>

typedef unsigned short u16;
typedef unsigned int u32;
typedef __attribute__((ext_vector_type(8))) _Float16 half8;  // fp16x8 MFMA frag
typedef __attribute__((ext_vector_type(8))) u16 ushort8;
typedef __attribute__((ext_vector_type(4))) float f32x4;

__device__ __forceinline__ float h2f(u16 u) {
    union { u16 u; _Float16 h; } c; c.u = u; return (float)c.h;
}
__device__ __forceinline__ u16 f2h(float f) {
    union { u16 u; _Float16 h; } c; c.h = (_Float16)f; return c.u;
}

// async global(16B) -> LDS, per-lane source addr, wave-linear LDS dest
__device__ __forceinline__ void gload16(void* lds, const void* g) {
    __builtin_amdgcn_global_load_lds(
        (const __attribute__((address_space(1))) u32*)g,
        (__attribute__((address_space(3))) u32*)lds,
        16, 0, 0);
}

// ---------------------------------------------------------------------------
// C[M,512] = A[M,512](fp16) @ Bt[512,512](fp16, [n][k]) + bias.
// OUTMODE 0: f32 store, 1: fp16 store. Stores guarded by row < Mout.
//
// 2-phase double-buffered K-loop: next tile's global_load_lds issued BEFORE
// current tile's ds_read+MFMA, one barrier per k-step (T3 minimal recipe) —
// HBM latency hides under compute instead of being drained immediately.
//
// LDS tile [128][32]u16, XOR slot-swizzle (verified round 6: conflicts -> 0):
// linear gload_lds dest + inverse-swizzled GLOBAL source column + swizzled
// read slot. slot'(row) = slot ^ ((row>>1)&3).
// ---------------------------------------------------------------------------
template <int OUTMODE>
__global__ __launch_bounds__(256) void gemm_f16(
    const u16* __restrict__ A, const u16* __restrict__ Bt,
    const float* __restrict__ bias, void* __restrict__ Cout, int Mout)
{
    __shared__ __align__(16) u16 As0[4096], As1[4096], Bs0[4096], Bs1[4096];

    const int tid  = threadIdx.x;
    const int wave = tid >> 6;
    const int lane = tid & 63;
    const int m0 = blockIdx.x * 128;
    const int n0 = blockIdx.y * 128;
    const int wr = (wave >> 1) * 64;
    const int wc = (wave & 1) * 64;

    f32x4 acc[4][4];
#pragma unroll
    for (int i = 0; i < 4; ++i)
#pragma unroll
        for (int j = 0; j < 4; ++j) acc[i][j] = (f32x4){0.f, 0.f, 0.f, 0.f};

    // staging: wave handles rows wave*32 .. +31 of the 128-row tile.
    const int srow  = lane >> 2;                              // 0..15
    const int scolG = ((lane & 3) ^ ((srow >> 1) & 3)) * 8;   // swizzled global col
    const size_t gOffA = (size_t)(m0 + wave * 32 + srow) * 512 + scolG;
    const size_t gOffB = (size_t)(n0 + wave * 32 + srow) * 512 + scolG;
    const int lOff = wave * 1024 + srow * 32 + (lane & 3) * 8;  // linear dest

    // read slots (swizzled)
    const int fR = ((lane & 15) >> 1) & 3;
    const int paOff = (wr + (lane & 15)) * 32 + ((lane >> 4) ^ fR) * 8;
    const int pbOff = (wc + (lane & 15)) * 32 + ((lane >> 4) ^ fR) * 8;

    auto STAGE = [&](u16* sa, u16* sb, int ko) {
        gload16(sa + lOff,       A  + gOffA + ko);
        gload16(sa + lOff + 512, A  + gOffA + ko + 16 * 512);
        gload16(sb + lOff,       Bt + gOffB + ko);
        gload16(sb + lOff + 512, Bt + gOffB + ko + 16 * 512);
    };
    auto COMPUTE = [&](const u16* sa, const u16* sb) {
        half8 af[4], bf[4];
#pragma unroll
        for (int i = 0; i < 4; ++i) af[i] = *(const half8*)(sa + paOff + i * 512);
#pragma unroll
        for (int j = 0; j < 4; ++j) bf[j] = *(const half8*)(sb + pbOff + j * 512);
#pragma unroll
        for (int i = 0; i < 4; ++i)
#pragma unroll
            for (int j = 0; j < 4; ++j)
                acc[i][j] = __builtin_amdgcn_mfma_f32_16x16x32_f16(
                    af[i], bf[j], acc[i][j], 0, 0, 0);
    };

    STAGE(As0, Bs0, 0);
    __syncthreads();                       // drains vmcnt(0): tile 0 ready
#pragma unroll
    for (int kt = 0; kt < 16; kt += 2) {
        STAGE(As1, Bs1, (kt + 1) * 32);    // issue next tile first
        COMPUTE(As0, Bs0);                 // compute current under the loads
        __syncthreads();                   // drain: tile kt+1 ready, As0 free
        if (kt + 2 < 16) STAGE(As0, Bs0, (kt + 2) * 32);
        COMPUTE(As1, Bs1);
        __syncthreads();
    }

    // epilogue: C/D layout col=lane&15, row=(lane>>4)*4+reg
    const int ccol  = n0 + wc + (lane & 15);
    const int crow0 = m0 + wr + (lane >> 4) * 4;
#pragma unroll
    for (int j = 0; j < 4; ++j) {
        const float b = bias[ccol + j * 16];
#pragma unroll
        for (int i = 0; i < 4; ++i) {
#pragma unroll
            for (int r = 0; r < 4; ++r) {
                int row = crow0 + i * 16 + r;
                if (row < Mout) {
                    float v = acc[i][j][r] + b;
                    size_t off = (size_t)row * 512 + ccol + j * 16;
                    if (OUTMODE == 0) ((float*)Cout)[off] = v;
                    else              ((u16*)Cout)[off] = f2h(v);
                }
            }
        }
    }
}

// ---------------------------------------------------------------------------
// prep: h f32 -> fp16, pad rows zeroed
// ---------------------------------------------------------------------------
__global__ __launch_bounds__(256) void conv_h(
    const float* __restrict__ h, u16* __restrict__ hh, int nN)
{
    int t = blockIdx.x * 256 + threadIdx.x;      // one thread = 8 elems
    size_t e = (size_t)t * 8;
    int row = (int)(e >> 9);
    ushort8 o;
    if (row < nN) {
        f32x4 a = *(const f32x4*)(h + e);
        f32x4 b = *(const f32x4*)(h + e + 4);
        float x[8] = {a.x, a.y, a.z, a.w, b.x, b.y, b.z, b.w};
#pragma unroll
        for (int i = 0; i < 8; ++i) o[i] = f2h(x[i]);
    } else {
        o = (ushort8){0,0,0,0,0,0,0,0};
    }
    *(ushort8*)(hh + e) = o;
}

// ---------------------------------------------------------------------------
// Weight transposes via LDS 64x65 tiles; coalesced global reads. fp16 out.
// z=0: Wqt[j][k] = Wq[k][perm(j)]   perm(j) = (j&63)*8 + (j>>6)
// z=1: Wkt[j][k] = Wk[k][perm(j)]
// z=2: Wot[c][j] = Wo[perm(j)][c]  + bias perms
// ---------------------------------------------------------------------------
__global__ __launch_bounds__(256) void conv_w(
    const float* __restrict__ Wq, const float* __restrict__ Wk,
    const float* __restrict__ Wo, const float* __restrict__ bq,
    const float* __restrict__ bk,
    u16* __restrict__ Wqt, u16* __restrict__ Wkt, u16* __restrict__ Wot,
    float* __restrict__ bqp, float* __restrict__ bkp)
{
    __shared__ float T[64][65];
    const int tid = threadIdx.x;
    const int z = blockIdx.z;
    const int X = blockIdx.x * 64;   // out-col tile (k for z<2, j for z=2)
    const int Y = blockIdx.y * 64;   // p-tile (z<2) / c-tile (z=2)

    const int r4 = tid >> 4;          // 0..15
    const int c4 = (tid & 15) * 4;    // 0..60
    if (z < 2) {
        const float* W = z ? Wk : Wq;
#pragma unroll
        for (int rr = 0; rr < 64; rr += 16) {
            f32x4 v = *(const f32x4*)(W + (size_t)(X + rr + r4) * 512 + Y + c4);
            T[rr + r4][c4 + 0] = v.x; T[rr + r4][c4 + 1] = v.y;
            T[rr + r4][c4 + 2] = v.z; T[rr + r4][c4 + 3] = v.w;
        }
    } else {
#pragma unroll
        for (int rr = 0; rr < 64; rr += 16) {
            int p2 = (rr + r4) * 8 + (X >> 6);   // perm(X + rr + r4)
            f32x4 v = *(const f32x4*)(Wo + (size_t)p2 * 512 + Y + c4);
            T[rr + r4][c4 + 0] = v.x; T[rr + r4][c4 + 1] = v.y;
            T[rr + r4][c4 + 2] = v.z; T[rr + r4][c4 + 3] = v.w;
        }
    }
    __syncthreads();

    // write: each thread emits 16 u16 (32B) of one output row
    const int cc = tid >> 2;
    const int ks = (tid & 3) * 16;
    const int pc = Y + cc;
    const int ro = (z < 2) ? ((pc & 7) * 64 + (pc >> 3)) : pc;
    ushort8 h0, h1;
#pragma unroll
    for (int t = 0; t < 8; ++t) {
        h0[t] = f2h(T[ks + t][cc]);
        h1[t] = f2h(T[ks + 8 + t][cc]);
    }
    size_t o = (size_t)ro * 512 + X + ks;
    if (z == 0) {
        *(ushort8*)(Wqt + o) = h0; *(ushort8*)(Wqt + o + 8) = h1;
    } else if (z == 1) {
        *(ushort8*)(Wkt + o) = h0; *(ushort8*)(Wkt + o + 8) = h1;
    } else {
        *(ushort8*)(Wot + o) = h0; *(ushort8*)(Wot + o + 8) = h1;
        if (blockIdx.x == 0 && blockIdx.y == 0) {
            for (int b = tid; b < 512; b += 256) {
                int pp = (b & 63) * 8 + (b >> 6);
                bqp[b] = bq[pp];
                bkp[b] = bk[pp];
            }
        }
    }
}

// ---------------------------------------------------------------------------
// CSR build: histogram -> hierarchical scan -> scatter (stores cols directly)
// ---------------------------------------------------------------------------
__global__ void hist_kernel(const int* __restrict__ rows, int* __restrict__ deg, int E)
{
    int i = blockIdx.x * 256 + threadIdx.x;
    if (i < E) atomicAdd(&deg[rows[i]], 1);
}

#define SCAN_CHUNK 2048

__global__ __launch_bounds__(256) void scan_partial(
    const int* __restrict__ deg, int* __restrict__ bsum, int n)
{
    int base = blockIdx.x * SCAN_CHUNK;
    int t = threadIdx.x;
    int s = 0;
    for (int i = t; i < SCAN_CHUNK; i += 256) {
        int g = base + i;
        s += (g < n) ? deg[g] : 0;
    }
#pragma unroll
    for (int off = 1; off < 64; off <<= 1) s += __shfl_xor(s, off, 64);
    __shared__ int ws[4];
    if ((t & 63) == 0) ws[t >> 6] = s;
    __syncthreads();
    if (t == 0) bsum[blockIdx.x] = ws[0] + ws[1] + ws[2] + ws[3];
}

__global__ __launch_bounds__(64) void scan_bsum(
    int* __restrict__ bsum, int nb, int* __restrict__ rowptr, int n)
{
    int l = threadIdx.x;
    int v = (l < nb) ? bsum[l] : 0;
    int orig = v;
#pragma unroll
    for (int off = 1; off < 64; off <<= 1) {
        int x = __shfl_up(v, off, 64);
        if (l >= off) v += x;
    }
    if (l < nb) bsum[l] = v - orig;       // exclusive
    if (l == nb - 1) rowptr[n] = v;       // total
}

__global__ __launch_bounds__(256) void scan_final(
    const int* __restrict__ deg, const int* __restrict__ bsum,
    int* __restrict__ rowptr, int* __restrict__ cursor, int n)
{
    int t = threadIdx.x;
    int base = blockIdx.x * SCAN_CHUNK + t * 8;
    int v[8];
    int s = 0;
#pragma unroll
    for (int i = 0; i < 8; ++i) {
        int g = base + i;
        v[i] = (g < n) ? deg[g] : 0;
        s += v[i];
    }
    int lane = t & 63, w = t >> 6;
    int inc = s;
#pragma unroll
    for (int off = 1; off < 64; off <<= 1) {
        int x = __shfl_up(inc, off, 64);
        if (lane >= off) inc += x;
    }
    __shared__ int wsum[4];
    if (lane == 63) wsum[w] = inc;
    __syncthreads();
    int excl = bsum[blockIdx.x] + inc - s;
    for (int i = 0; i < w; ++i) excl += wsum[i];
#pragma unroll
    for (int i = 0; i < 8; ++i) {
        int g = base + i;
        if (g < n) { rowptr[g] = excl; cursor[g] = excl; }
        excl += v[i];
    }
}

__global__ void scatter_kernel(const int* __restrict__ rows, const int* __restrict__ cols,
                               int* __restrict__ cursor, int* __restrict__ colc, int E)
{
    int i = blockIdx.x * 256 + threadIdx.x;
    if (i < E) {
        int pos = atomicAdd(&cursor[rows[i]], 1);
        colc[pos] = cols[i];
    }
}

// ---------------------------------------------------------------------------
// Fused SDDMM + online segment softmax + SpMM. Head-major layout:
// lane l -> head l>>3, dims (l&7)*8..+7. One wave per node, 4 nodes/block.
// 4-edge unroll + depth-4 prefetch; one defer-max check per 4-edge group.
// v == k (source bug): the K row loaded for the dot is reused for aggregation.
// ---------------------------------------------------------------------------
__global__ __launch_bounds__(256) void node_agg(
    const u16* __restrict__ Qh, const u16* __restrict__ Kb,
    const int* __restrict__ rowptr, const int* __restrict__ colc,
    u16* __restrict__ aggb, int nN)
{
    int node = blockIdx.x * 4 + (threadIdx.x >> 6);
    int lane = threadIdx.x & 63;
    if (node >= nN) return;
    size_t base = (size_t)node * 512 + lane * 8;

    float q[8];
    {
        ushort8 qv = __builtin_nontemporal_load((const ushort8*)(Qh + base));
#pragma unroll
        for (int i = 0; i < 8; ++i) q[i] = h2f(qv[i]);
    }

    int start = rowptr[node];
    int deg   = rowptr[node + 1] - start;
    const int* cp = colc + start;
    const size_t loff = (size_t)lane * 8;

    float m = -__builtin_inff();
    float den = 0.f;
    float acc[8];
#pragma unroll
    for (int i = 0; i < 8; ++i) acc[i] = 0.f;

    if (deg > 0) {
        const int dl = deg - 1;
        ushort8 k0 = *(const ushort8*)(Kb + (size_t)cp[0] * 512 + loff);
        ushort8 k1 = *(const ushort8*)(Kb + (size_t)cp[1 < dl ? 1 : dl] * 512 + loff);
        ushort8 k2 = *(const ushort8*)(Kb + (size_t)cp[2 < dl ? 2 : dl] * 512 + loff);
        ushort8 k3 = *(const ushort8*)(Kb + (size_t)cp[3 < dl ? 3 : dl] * 512 + loff);
        for (int j = 0; j < deg; j += 4) {
            int i4 = j + 4 < dl ? j + 4 : dl;
            int i5 = j + 5 < dl ? j + 5 : dl;
            int i6 = j + 6 < dl ? j + 6 : dl;
            int i7 = j + 7 < dl ? j + 7 : dl;
            ushort8 n0 = *(const ushort8*)(Kb + (size_t)cp[i4] * 512 + loff);
            ushort8 n1 = *(const ushort8*)(Kb + (size_t)cp[i5] * 512 + loff);
            ushort8 n2 = *(const ushort8*)(Kb + (size_t)cp[i6] * 512 + loff);
            ushort8 n3 = *(const ushort8*)(Kb + (size_t)cp[i7] * 512 + loff);

            float kf0[8], kf1[8], kf2[8], kf3[8];
#pragma unroll
            for (int i = 0; i < 8; ++i) {
                kf0[i] = h2f(k0[i]); kf1[i] = h2f(k1[i]);
                kf2[i] = h2f(k2[i]); kf3[i] = h2f(k3[i]);
            }
            float p0 = 0.f, p1 = 0.f, p2 = 0.f, p3 = 0.f;
#pragma unroll
            for (int i = 0; i < 8; ++i) {
                p0 = fmaf(q[i], kf0[i], p0);
                p1 = fmaf(q[i], kf1[i], p1);
                p2 = fmaf(q[i], kf2[i], p2);
                p3 = fmaf(q[i], kf3[i], p3);
            }
#pragma unroll
            for (int off = 1; off < 8; off <<= 1) {
                p0 += __shfl_xor(p0, off, 64);
                p1 += __shfl_xor(p1, off, 64);
                p2 += __shfl_xor(p2, off, 64);
                p3 += __shfl_xor(p3, off, 64);
            }

            // defer-max (T13, THR=8): one check per 4-edge group
            float pm = fmaxf(fmaxf(p0, p1), fmaxf(p2, p3));
            if (__any(pm > m + 8.f)) {
                float mn = fmaxf(m, pm);
                float sc = __expf(m - mn);   // first group: exp(-inf)=0
                den *= sc;
#pragma unroll
                for (int i = 0; i < 8; ++i) acc[i] *= sc;
                m = mn;
            }
            float w0 = __expf(p0 - m);       // each bounded by e^8
            float w1 = (j + 1 < deg) ? __expf(p1 - m) : 0.f;
            float w2 = (j + 2 < deg) ? __expf(p2 - m) : 0.f;
            float w3 = (j + 3 < deg) ? __expf(p3 - m) : 0.f;
            den += (w0 + w1) + (w2 + w3);
#pragma unroll
            for (int i = 0; i < 8; ++i)
                acc[i] = fmaf(w3, kf3[i], fmaf(w2, kf2[i],
                         fmaf(w1, kf1[i], fmaf(w0, kf0[i], acc[i]))));
            k0 = n0; k1 = n1; k2 = n2; k3 = n3;
        }
    }

    float inv = (deg > 0) ? 1.f / den : 0.f;
    ushort8 o;
#pragma unroll
    for (int i = 0; i < 8; ++i) o[i] = f2h(acc[i] * inv);
    __builtin_nontemporal_store(o, (ushort8*)(aggb + base));
}

// ---------------------------------------------------------------------------
extern "C" void kernel_launch(void* const* d_in, const int* in_sizes, int n_in,
                              void* d_out, int out_size, void* d_ws, size_t ws_size,
                              hipStream_t stream)
{
    const float* h  = (const float*)d_in[0];
    const float* Wq = (const float*)d_in[1];
    const float* bq = (const float*)d_in[2];
    const float* Wk = (const float*)d_in[3];
    const float* bk = (const float*)d_in[4];
    const float* Wo = (const float*)d_in[5];
    const float* bo = (const float*)d_in[6];
    const int* rows = (const int*)d_in[7];
    const int* cols = (const int*)d_in[8];
    float* out = (float*)d_out;

    const int HID = 512;
    const int nN  = in_sizes[0] / HID;              // 25000
    const int E   = in_sizes[7];                    // 400000
    const int nPad = (nN + 127) & ~127;             // 25088
    const int nb = (nN + SCAN_CHUNK - 1) / SCAN_CHUNK;  // 13

    // workspace layout (all 16B-aligned), everything fp16 now (~81 MB)
    char* w = (char*)d_ws;
    u16* Kb  = (u16*)w;  w += (size_t)nPad * HID * 2;  // 25.7 MB
    u16* hh  = (u16*)w;  w += (size_t)nPad * HID * 2;  // 25.7 MB (reused as agg)
    u16* Qh  = (u16*)w;  w += (size_t)nPad * HID * 2;  // 25.7 MB
    u16* Wqt = (u16*)w;  w += 512 * 512 * 2;
    u16* Wkt = (u16*)w;  w += 512 * 512 * 2;
    u16* Wot = (u16*)w;  w += 512 * 512 * 2;
    float* bqp = (float*)w;  w += 512 * 4;
    float* bkp = (float*)w;  w += 512 * 4;
    int* rowptr = (int*)w;   w += (size_t)(nN + 1) * 4;
    int* cursor = (int*)w;   w += (size_t)nN * 4;
    int* deg    = (int*)w;   w += (size_t)nN * 4;
    int* bsum   = (int*)w;   w += 64 * 4;
    int* colc   = (int*)w;   /* E*4 */

    // CSR build
    hipMemsetAsync(deg, 0, (size_t)nN * sizeof(int), stream);
    hist_kernel<<<(E + 255) / 256, 256, 0, stream>>>(rows, deg, E);
    scan_partial<<<nb, 256, 0, stream>>>(deg, bsum, nN);
    scan_bsum<<<1, 64, 0, stream>>>(bsum, nb, rowptr, nN);
    scan_final<<<nb, 256, 0, stream>>>(deg, bsum, rowptr, cursor, nN);
    scatter_kernel<<<(E + 255) / 256, 256, 0, stream>>>(rows, cols, cursor, colc, E);

    // conversions (all fp16)
    conv_h<<<(nPad * (HID / 8) + 255) / 256, 256, 0, stream>>>(h, hh, nN);
    conv_w<<<dim3(8, 8, 3), 256, 0, stream>>>(Wq, Wk, Wo, bq, bk,
                                              Wqt, Wkt, Wot, bqp, bkp);

    // projections (head-major outputs), single-pass fp16 MFMA
    dim3 gg(nPad / 128, 4);
    gemm_f16<1><<<gg, 256, 0, stream>>>(hh, Wqt, bqp, Qh, nPad);   // Q fp16
    gemm_f16<1><<<gg, 256, 0, stream>>>(hh, Wkt, bkp, Kb, nPad);   // K fp16

    // fused SDDMM + softmax + aggregate -> fp16 agg (overwrites hh)
    node_agg<<<(nN + 3) / 4, 256, 0, stream>>>(Qh, Kb, rowptr, colc, hh, nN);

    // output projection -> f32 out
    gemm_f16<0><<<gg, 256, 0, stream>>>(hh, Wot, bo, out, nN);
}

// Round 9
// 234.784 us; speedup vs baseline: 1.3583x; 1.1230x over previous
//
#include <hip/hip_runtime.h>
#include <math.h>

typedef unsigned short u16;
typedef unsigned int u32;
typedef __attribute__((ext_vector_type(8))) _Float16 half8;   // fp16x8
typedef __attribute__((ext_vector_type(2))) _Float16 half2v;  // fp16x2
typedef __attribute__((ext_vector_type(8))) u16 ushort8;
typedef __attribute__((ext_vector_type(4))) float f32x4;

__device__ __forceinline__ u16 f2h(float f) {
    union { u16 u; _Float16 h; } c; c.h = (_Float16)f; return c.u;
}

#if __has_builtin(__builtin_amdgcn_fdot2)
#define FDOT2(a, b, c) __builtin_amdgcn_fdot2((a), (b), (c), false)
#else
#define FDOT2(a, b, c) fmaf((float)(a)[0], (float)(b)[0], \
                        fmaf((float)(a)[1], (float)(b)[1], (c)))
#endif

// async global(16B) -> LDS, per-lane source addr, wave-linear LDS dest
__device__ __forceinline__ void gload16(void* lds, const void* g) {
    __builtin_amdgcn_global_load_lds(
        (const __attribute__((address_space(1))) u32*)g,
        (__attribute__((address_space(3))) u32*)lds,
        16, 0, 0);
}

// ---------------------------------------------------------------------------
// GEMM body: C[M,512] = A[M,512](fp16) @ Bt[512,512](fp16,[n][k]) + bias.
// 2-phase double-buffered K-loop (T3 minimal): next tile's global_load_lds
// issued BEFORE current tile's ds_read+MFMA, one barrier per k-step.
// LDS tile [128][32]u16, XOR slot-swizzle (verified: bank conflicts -> 0):
// linear gload_lds dest + inverse-swizzled GLOBAL source col + swizzled read.
// ---------------------------------------------------------------------------
template <int OUTMODE>   // 0: f32 store, 1: fp16 store
__device__ __forceinline__ void gemm_body(
    const u16* A, const u16* Bt, const float* bias, void* Cout, int Mout,
    int m0, int n0, u16* As0, u16* As1, u16* Bs0, u16* Bs1)
{
    const int tid  = threadIdx.x;
    const int wave = tid >> 6;
    const int lane = tid & 63;
    const int wr = (wave >> 1) * 64;
    const int wc = (wave & 1) * 64;

    f32x4 acc[4][4];
#pragma unroll
    for (int i = 0; i < 4; ++i)
#pragma unroll
        for (int j = 0; j < 4; ++j) acc[i][j] = (f32x4){0.f, 0.f, 0.f, 0.f};

    const int srow  = lane >> 2;                              // 0..15
    const int scolG = ((lane & 3) ^ ((srow >> 1) & 3)) * 8;   // swizzled global col
    const size_t gOffA = (size_t)(m0 + wave * 32 + srow) * 512 + scolG;
    const size_t gOffB = (size_t)(n0 + wave * 32 + srow) * 512 + scolG;
    const int lOff = wave * 1024 + srow * 32 + (lane & 3) * 8;  // linear dest

    const int fR = ((lane & 15) >> 1) & 3;
    const int paOff = (wr + (lane & 15)) * 32 + ((lane >> 4) ^ fR) * 8;
    const int pbOff = (wc + (lane & 15)) * 32 + ((lane >> 4) ^ fR) * 8;

    auto STAGE = [&](u16* sa, u16* sb, int ko) {
        gload16(sa + lOff,       A  + gOffA + ko);
        gload16(sa + lOff + 512, A  + gOffA + ko + 16 * 512);
        gload16(sb + lOff,       Bt + gOffB + ko);
        gload16(sb + lOff + 512, Bt + gOffB + ko + 16 * 512);
    };
    auto COMPUTE = [&](const u16* sa, const u16* sb) {
        half8 af[4], bf[4];
#pragma unroll
        for (int i = 0; i < 4; ++i) af[i] = *(const half8*)(sa + paOff + i * 512);
#pragma unroll
        for (int j = 0; j < 4; ++j) bf[j] = *(const half8*)(sb + pbOff + j * 512);
#pragma unroll
        for (int i = 0; i < 4; ++i)
#pragma unroll
            for (int j = 0; j < 4; ++j)
                acc[i][j] = __builtin_amdgcn_mfma_f32_16x16x32_f16(
                    af[i], bf[j], acc[i][j], 0, 0, 0);
    };

    STAGE(As0, Bs0, 0);
    __syncthreads();
#pragma unroll
    for (int kt = 0; kt < 16; kt += 2) {
        STAGE(As1, Bs1, (kt + 1) * 32);
        COMPUTE(As0, Bs0);
        __syncthreads();
        if (kt + 2 < 16) STAGE(As0, Bs0, (kt + 2) * 32);
        COMPUTE(As1, Bs1);
        __syncthreads();
    }

    const int ccol  = n0 + wc + (lane & 15);
    const int crow0 = m0 + wr + (lane >> 4) * 4;
#pragma unroll
    for (int j = 0; j < 4; ++j) {
        const float b = bias[ccol + j * 16];
#pragma unroll
        for (int i = 0; i < 4; ++i) {
#pragma unroll
            for (int r = 0; r < 4; ++r) {
                int row = crow0 + i * 16 + r;
                if (row < Mout) {
                    float v = acc[i][j][r] + b;
                    size_t off = (size_t)row * 512 + ccol + j * 16;
                    if (OUTMODE == 0) ((float*)Cout)[off] = v;
                    else              ((u16*)Cout)[off] = f2h(v);
                }
            }
        }
    }
}

// Q and K projections in ONE dispatch: blockIdx.z selects output.
__global__ __launch_bounds__(256) void gemm_qk(
    const u16* __restrict__ hh, const u16* __restrict__ Wqt,
    const u16* __restrict__ Wkt, const float* __restrict__ bqp,
    const float* __restrict__ bkp, u16* __restrict__ Qh,
    u16* __restrict__ Kb, int nPad)
{
    __shared__ __align__(16) u16 As0[4096], As1[4096], Bs0[4096], Bs1[4096];
    const u16* Bt = blockIdx.z ? Wkt : Wqt;
    const float* bias = blockIdx.z ? bkp : bqp;
    u16* out = blockIdx.z ? Kb : Qh;
    gemm_body<1>(hh, Bt, bias, out, nPad, blockIdx.x * 128, blockIdx.y * 128,
                 As0, As1, Bs0, Bs1);
}

__global__ __launch_bounds__(256) void gemm_wo(
    const u16* __restrict__ A, const u16* __restrict__ Wot,
    const float* __restrict__ bo, float* __restrict__ C, int Mout)
{
    __shared__ __align__(16) u16 As0[4096], As1[4096], Bs0[4096], Bs1[4096];
    gemm_body<0>(A, Wot, bo, C, Mout, blockIdx.x * 128, blockIdx.y * 128,
                 As0, As1, Bs0, Bs1);
}

// ---------------------------------------------------------------------------
// prep: fused conv_h (h f32 -> fp16, pad zeroed) + hist + conv_w.
// Grid partition: [0,nbH) conv_h, [nbH,nbH+nbE) hist, [nbH+nbE,+192) conv_w.
// ---------------------------------------------------------------------------
__global__ __launch_bounds__(256) void prep(
    const float* __restrict__ h, u16* __restrict__ hh, int nN,
    const int* __restrict__ rows, int* __restrict__ deg, int E,
    const float* __restrict__ Wq, const float* __restrict__ Wk,
    const float* __restrict__ Wo, const float* __restrict__ bq,
    const float* __restrict__ bk,
    u16* __restrict__ Wqt, u16* __restrict__ Wkt, u16* __restrict__ Wot,
    float* __restrict__ bqp, float* __restrict__ bkp,
    int nbH, int nbE)
{
    __shared__ float T[64][65];
    const int tid = threadIdx.x;
    const int b = blockIdx.x;

    if (b < nbH) {
        // ---- conv_h ----
        int t = b * 256 + tid;
        size_t e = (size_t)t * 8;
        int row = (int)(e >> 9);
        ushort8 o;
        if (row < nN) {
            f32x4 a = *(const f32x4*)(h + e);
            f32x4 bb = *(const f32x4*)(h + e + 4);
            float x[8] = {a.x, a.y, a.z, a.w, bb.x, bb.y, bb.z, bb.w};
#pragma unroll
            for (int i = 0; i < 8; ++i) o[i] = f2h(x[i]);
        } else {
            o = (ushort8){0,0,0,0,0,0,0,0};
        }
        *(ushort8*)(hh + e) = o;
        return;
    }
    if (b < nbH + nbE) {
        // ---- hist ----
        int i = (b - nbH) * 256 + tid;
        if (i < E) atomicAdd(&deg[rows[i]], 1);
        return;
    }
    // ---- conv_w ----  (192 blocks: z = rem>>6, by = (rem&63)>>3, bx = rem&7)
    int rem = b - nbH - nbE;
    const int z = rem >> 6;
    const int X = (rem & 7) * 64;
    const int Y = ((rem >> 3) & 7) * 64;

    const int r4 = tid >> 4;
    const int c4 = (tid & 15) * 4;
    if (z < 2) {
        const float* W = z ? Wk : Wq;
#pragma unroll
        for (int rr = 0; rr < 64; rr += 16) {
            f32x4 v = *(const f32x4*)(W + (size_t)(X + rr + r4) * 512 + Y + c4);
            T[rr + r4][c4 + 0] = v.x; T[rr + r4][c4 + 1] = v.y;
            T[rr + r4][c4 + 2] = v.z; T[rr + r4][c4 + 3] = v.w;
        }
    } else {
#pragma unroll
        for (int rr = 0; rr < 64; rr += 16) {
            int p2 = (rr + r4) * 8 + (X >> 6);   // perm(X + rr + r4)
            f32x4 v = *(const f32x4*)(Wo + (size_t)p2 * 512 + Y + c4);
            T[rr + r4][c4 + 0] = v.x; T[rr + r4][c4 + 1] = v.y;
            T[rr + r4][c4 + 2] = v.z; T[rr + r4][c4 + 3] = v.w;
        }
    }
    __syncthreads();

    const int cc = tid >> 2;
    const int ks = (tid & 3) * 16;
    const int pc = Y + cc;
    const int ro = (z < 2) ? ((pc & 7) * 64 + (pc >> 3)) : pc;
    ushort8 h0, h1;
#pragma unroll
    for (int t = 0; t < 8; ++t) {
        h0[t] = f2h(T[ks + t][cc]);
        h1[t] = f2h(T[ks + 8 + t][cc]);
    }
    size_t o = (size_t)ro * 512 + X + ks;
    if (z == 0) {
        *(ushort8*)(Wqt + o) = h0; *(ushort8*)(Wqt + o + 8) = h1;
    } else if (z == 1) {
        *(ushort8*)(Wkt + o) = h0; *(ushort8*)(Wkt + o + 8) = h1;
    } else {
        *(ushort8*)(Wot + o) = h0; *(ushort8*)(Wot + o + 8) = h1;
        if (rem == 128) {   // z==2, bx==0, by==0
            for (int bi = tid; bi < 512; bi += 256) {
                int pp = (bi & 63) * 8 + (bi >> 6);
                bqp[bi] = bq[pp];
                bkp[bi] = bk[pp];
            }
        }
    }
}

// ---------------------------------------------------------------------------
// CSR scan: partial sums (13 blocks) -> final (13 blocks, self-scans bsum)
// ---------------------------------------------------------------------------
#define SCAN_CHUNK 2048

__global__ __launch_bounds__(256) void scan_partial(
    const int* __restrict__ deg, int* __restrict__ bsum, int n)
{
    int base = blockIdx.x * SCAN_CHUNK;
    int t = threadIdx.x;
    int s = 0;
    for (int i = t; i < SCAN_CHUNK; i += 256) {
        int g = base + i;
        s += (g < n) ? deg[g] : 0;
    }
#pragma unroll
    for (int off = 1; off < 64; off <<= 1) s += __shfl_xor(s, off, 64);
    __shared__ int ws[4];
    if ((t & 63) == 0) ws[t >> 6] = s;
    __syncthreads();
    if (t == 0) bsum[blockIdx.x] = ws[0] + ws[1] + ws[2] + ws[3];
}

__global__ __launch_bounds__(256) void scan_final(
    const int* __restrict__ deg, const int* __restrict__ bsum,
    int* __restrict__ rowptr, int* __restrict__ cursor, int n, int nb)
{
    // every block redundantly scans the nb block sums (broadcast loads)
    int boff = 0, total = 0;
    for (int i = 0; i < nb; ++i) {
        int v = bsum[i];
        if (i < (int)blockIdx.x) boff += v;
        total += v;
    }
    int t = threadIdx.x;
    int base = blockIdx.x * SCAN_CHUNK + t * 8;
    int v[8];
    int s = 0;
#pragma unroll
    for (int i = 0; i < 8; ++i) {
        int g = base + i;
        v[i] = (g < n) ? deg[g] : 0;
        s += v[i];
    }
    int lane = t & 63, w = t >> 6;
    int inc = s;
#pragma unroll
    for (int off = 1; off < 64; off <<= 1) {
        int x = __shfl_up(inc, off, 64);
        if (lane >= off) inc += x;
    }
    __shared__ int wsum[4];
    if (lane == 63) wsum[w] = inc;
    __syncthreads();
    int excl = boff + inc - s;
    for (int i = 0; i < w; ++i) excl += wsum[i];
#pragma unroll
    for (int i = 0; i < 8; ++i) {
        int g = base + i;
        if (g < n) { rowptr[g] = excl; cursor[g] = excl; }
        excl += v[i];
    }
    if (blockIdx.x == 0 && t == 0) rowptr[n] = total;
}

__global__ void scatter_kernel(const int* __restrict__ rows, const int* __restrict__ cols,
                               int* __restrict__ cursor, int* __restrict__ colc, int E)
{
    int i = blockIdx.x * 256 + threadIdx.x;
    if (i < E) {
        int pos = atomicAdd(&cursor[rows[i]], 1);
        colc[pos] = cols[i];
    }
}

// ---------------------------------------------------------------------------
// Fused SDDMM + online segment softmax + SpMM. Head-major layout:
// lane l -> head l>>3, dims (l&7)*8..+7. One wave per node, 4 nodes/block.
// 4-edge unroll + depth-4 prefetch. Packed fp16 math: scores via
// v_dot2_f32_f16 (f32 accumulate), aggregation via packed fp16 FMA (fp16 acc,
// defer-max THR=4 so w <= e^4: den <= deg*54.6, acc far from fp16 overflow).
// v == k (source bug): K row loaded for the dot is reused for aggregation.
// ---------------------------------------------------------------------------
__global__ __launch_bounds__(256) void node_agg(
    const u16* __restrict__ Qh, const u16* __restrict__ Kb,
    const int* __restrict__ rowptr, const int* __restrict__ colc,
    u16* __restrict__ aggb, int nN)
{
    int node = blockIdx.x * 4 + (threadIdx.x >> 6);
    int lane = threadIdx.x & 63;
    if (node >= nN) return;
    size_t base = (size_t)node * 512 + lane * 8;

    half8 qv = __builtin_nontemporal_load((const half8*)(Qh + base));
    half2v q2[4];
#pragma unroll
    for (int i = 0; i < 4; ++i) q2[i] = (half2v){qv[2 * i], qv[2 * i + 1]};

    int start = rowptr[node];
    int deg   = rowptr[node + 1] - start;
    const int* cp = colc + start;
    const size_t loff = (size_t)lane * 8;

    float m = -__builtin_inff();
    float den = 0.f;
    half2v acc2[4];
#pragma unroll
    for (int i = 0; i < 4; ++i) acc2[i] = (half2v){(_Float16)0.f, (_Float16)0.f};

    if (deg > 0) {
        const int dl = deg - 1;
        half8 k0 = *(const half8*)(Kb + (size_t)cp[0] * 512 + loff);
        half8 k1 = *(const half8*)(Kb + (size_t)cp[1 < dl ? 1 : dl] * 512 + loff);
        half8 k2 = *(const half8*)(Kb + (size_t)cp[2 < dl ? 2 : dl] * 512 + loff);
        half8 k3 = *(const half8*)(Kb + (size_t)cp[3 < dl ? 3 : dl] * 512 + loff);
        for (int j = 0; j < deg; j += 4) {
            int i4 = j + 4 < dl ? j + 4 : dl;
            int i5 = j + 5 < dl ? j + 5 : dl;
            int i6 = j + 6 < dl ? j + 6 : dl;
            int i7 = j + 7 < dl ? j + 7 : dl;
            half8 n0 = *(const half8*)(Kb + (size_t)cp[i4] * 512 + loff);
            half8 n1 = *(const half8*)(Kb + (size_t)cp[i5] * 512 + loff);
            half8 n2 = *(const half8*)(Kb + (size_t)cp[i6] * 512 + loff);
            half8 n3 = *(const half8*)(Kb + (size_t)cp[i7] * 512 + loff);

            float p0 = 0.f, p1 = 0.f, p2 = 0.f, p3 = 0.f;
#pragma unroll
            for (int i = 0; i < 4; ++i) {
                half2v a = q2[i];
                half2v b0 = (half2v){k0[2 * i], k0[2 * i + 1]};
                half2v b1 = (half2v){k1[2 * i], k1[2 * i + 1]};
                half2v b2 = (half2v){k2[2 * i], k2[2 * i + 1]};
                half2v b3 = (half2v){k3[2 * i], k3[2 * i + 1]};
                p0 = FDOT2(a, b0, p0);
                p1 = FDOT2(a, b1, p1);
                p2 = FDOT2(a, b2, p2);
                p3 = FDOT2(a, b3, p3);
            }
#pragma unroll
            for (int off = 1; off < 8; off <<= 1) {
                p0 += __shfl_xor(p0, off, 64);
                p1 += __shfl_xor(p1, off, 64);
                p2 += __shfl_xor(p2, off, 64);
                p3 += __shfl_xor(p3, off, 64);
            }

            // defer-max (THR=4, fp16-acc-safe): one check per 4-edge group
            float pm = fmaxf(fmaxf(p0, p1), fmaxf(p2, p3));
            if (__any(pm > m + 4.f)) {
                float mn = fmaxf(m, pm);
                float sc = __expf(m - mn);   // first group: exp(-inf)=0
                den *= sc;
                _Float16 sch = (_Float16)sc;
                half2v sc2 = {sch, sch};
#pragma unroll
                for (int i = 0; i < 4; ++i) acc2[i] *= sc2;
                m = mn;
            }
            float w0 = __expf(p0 - m);       // each bounded by e^4
            float w1 = (j + 1 < deg) ? __expf(p1 - m) : 0.f;
            float w2 = (j + 2 < deg) ? __expf(p2 - m) : 0.f;
            float w3 = (j + 3 < deg) ? __expf(p3 - m) : 0.f;
            den += (w0 + w1) + (w2 + w3);
            _Float16 h0 = (_Float16)w0, h1 = (_Float16)w1;
            _Float16 h2 = (_Float16)w2, h3 = (_Float16)w3;
            half2v w02 = {h0, h0}, w12 = {h1, h1}, w22 = {h2, h2}, w32 = {h3, h3};
#pragma unroll
            for (int i = 0; i < 4; ++i) {
                half2v b0 = (half2v){k0[2 * i], k0[2 * i + 1]};
                half2v b1 = (half2v){k1[2 * i], k1[2 * i + 1]};
                half2v b2 = (half2v){k2[2 * i], k2[2 * i + 1]};
                half2v b3 = (half2v){k3[2 * i], k3[2 * i + 1]};
                acc2[i] += w02 * b0;
                acc2[i] += w12 * b1;
                acc2[i] += w22 * b2;
                acc2[i] += w32 * b3;
            }
            k0 = n0; k1 = n1; k2 = n2; k3 = n3;
        }
    }

    float inv = (deg > 0) ? 1.f / den : 0.f;
    ushort8 o;
#pragma unroll
    for (int i = 0; i < 4; ++i) {
        o[2 * i]     = f2h((float)acc2[i][0] * inv);
        o[2 * i + 1] = f2h((float)acc2[i][1] * inv);
    }
    __builtin_nontemporal_store(o, (ushort8*)(aggb + base));
}

// ---------------------------------------------------------------------------
extern "C" void kernel_launch(void* const* d_in, const int* in_sizes, int n_in,
                              void* d_out, int out_size, void* d_ws, size_t ws_size,
                              hipStream_t stream)
{
    const float* h  = (const float*)d_in[0];
    const float* Wq = (const float*)d_in[1];
    const float* bq = (const float*)d_in[2];
    const float* Wk = (const float*)d_in[3];
    const float* bk = (const float*)d_in[4];
    const float* Wo = (const float*)d_in[5];
    const float* bo = (const float*)d_in[6];
    const int* rows = (const int*)d_in[7];
    const int* cols = (const int*)d_in[8];
    float* out = (float*)d_out;

    const int HID = 512;
    const int nN  = in_sizes[0] / HID;              // 25000
    const int E   = in_sizes[7];                    // 400000
    const int nPad = (nN + 127) & ~127;             // 25088
    const int nb = (nN + SCAN_CHUNK - 1) / SCAN_CHUNK;  // 13
    const int nbH = nPad * (HID / 8) / 256;         // conv_h blocks: 6272
    const int nbE = (E + 255) / 256;                // hist blocks: 1563

    // workspace layout (all 16B-aligned), fp16 throughout (~81 MB)
    char* w = (char*)d_ws;
    u16* Kb  = (u16*)w;  w += (size_t)nPad * HID * 2;  // 25.7 MB
    u16* hh  = (u16*)w;  w += (size_t)nPad * HID * 2;  // 25.7 MB (reused as agg)
    u16* Qh  = (u16*)w;  w += (size_t)nPad * HID * 2;  // 25.7 MB
    u16* Wqt = (u16*)w;  w += 512 * 512 * 2;
    u16* Wkt = (u16*)w;  w += 512 * 512 * 2;
    u16* Wot = (u16*)w;  w += 512 * 512 * 2;
    float* bqp = (float*)w;  w += 512 * 4;
    float* bkp = (float*)w;  w += 512 * 4;
    int* rowptr = (int*)w;   w += (size_t)(nN + 1) * 4;
    int* cursor = (int*)w;   w += (size_t)nN * 4;
    int* deg    = (int*)w;   w += (size_t)nN * 4;
    int* bsum   = (int*)w;   w += 64 * 4;
    int* colc   = (int*)w;   /* E*4 */

    (void)hipMemsetAsync(deg, 0, (size_t)nN * sizeof(int), stream);

    // fused conv_h + hist + conv_w
    prep<<<nbH + nbE + 192, 256, 0, stream>>>(
        h, hh, nN, rows, deg, E, Wq, Wk, Wo, bq, bk,
        Wqt, Wkt, Wot, bqp, bkp, nbH, nbE);

    // CSR: partial scan -> final scan (self-scans block sums) -> scatter
    scan_partial<<<nb, 256, 0, stream>>>(deg, bsum, nN);
    scan_final<<<nb, 256, 0, stream>>>(deg, bsum, rowptr, cursor, nN, nb);
    scatter_kernel<<<(E + 255) / 256, 256, 0, stream>>>(rows, cols, cursor, colc, E);

    // Q + K projections in one dispatch (head-major outputs, fp16)
    gemm_qk<<<dim3(nPad / 128, 4, 2), 256, 0, stream>>>(
        hh, Wqt, Wkt, bqp, bkp, Qh, Kb, nPad);

    // fused SDDMM + softmax + aggregate -> fp16 agg (overwrites hh)
    node_agg<<<(nN + 3) / 4, 256, 0, stream>>>(Qh, Kb, rowptr, colc, hh, nN);

    // output projection -> f32 out
    gemm_wo<<<dim3(nPad / 128, 4), 256, 0, stream>>>(hh, Wot, bo, out, nN);
}